// Round 17
// baseline (376.573 us; speedup 1.0000x reference)
//
#include <hip/hip_runtime.h>
#include <hip/hip_bf16.h>

typedef __attribute__((ext_vector_type(8))) short bf16x8;
typedef __attribute__((ext_vector_type(4))) float f32x4;

constexpr int cB = 512, cNN = 96, cNC = 32, cF = 128, cE = 128,
              cH = 8, cDH = 16, cFF = 512, cD = 4, cMC = 64;
constexpr int TOK = cB * cF;

__device__ __forceinline__ float bf2f(unsigned short u) {
  union { float f; unsigned i; } v; v.i = ((unsigned)u) << 16; return v.f;
}
__device__ __forceinline__ unsigned short f2bf(float f) {
  __hip_bfloat16 h = __float2bfloat16(f);
  return *reinterpret_cast<unsigned short*>(&h);
}
__device__ __forceinline__ unsigned packbf(float a, float b) {
  __hip_bfloat162 h = __float22bfloat162_rn(make_float2(a, b));
  return *reinterpret_cast<unsigned*>(&h);
}
// XOR-swizzle of 16B-chunk index within aligned 8-chunk groups (involution)
__device__ __forceinline__ int swz(int c, int r) {
  return (c & ~7) | ((c & 7) ^ (r & 7));
}

#define GLD16(g, l) __builtin_amdgcn_global_load_lds( \
    (const __attribute__((address_space(1))) void*)(g), \
    (__attribute__((address_space(3))) void*)(l), 16, 0, 0)

// ---------------------------------------------------------------- setup
// one launch: pe table + all 6 weight packs, range-dispatched on blockIdx.
// Wq is scaled by 0.25*log2(e) so attn softmax can use exp2 directly.
__global__ __launch_bounds__(256) void setup_kernel(
    const float* __restrict__ Wq, const float* __restrict__ Wk,
    const float* __restrict__ Wv, const float* __restrict__ Wo,
    const float* __restrict__ W1, const float* __restrict__ W2,
    unsigned short* __restrict__ Wqkv_t, unsigned short* __restrict__ Wo_t,
    unsigned short* __restrict__ W1_t, unsigned short* __restrict__ W2_t,
    float* __restrict__ pe)
{
  int bid = blockIdx.x;
  if (bid < 64) {
    int idx = bid * 256 + threadIdx.x;              // 128*128
    int f = idx >> 7, e = idx & 127;
    int i = e >> 1;
    float ang = (float)f * expf(-(float)(2 * i) * 0.07195578415606394f);
    pe[idx] = (e & 1) ? cosf(ang) : sinf(ang);
    return;
  }
  const float* src; unsigned short* dst;
  int K, N, nStride, nOff, base;
  float scale = 1.0f;
  if (bid < 320)       { src = Wq; dst = Wqkv_t; K = 128; N = 128; nStride = 384; nOff = 0;   base = 64;
                         scale = 0.3606737602222409f; }   // 0.25 * log2(e)
  else if (bid < 576)  { src = Wk; dst = Wqkv_t; K = 128; N = 128; nStride = 384; nOff = 128; base = 320; }
  else if (bid < 832)  { src = Wv; dst = Wqkv_t; K = 128; N = 128; nStride = 384; nOff = 256; base = 576; }
  else if (bid < 1088) { src = Wo; dst = Wo_t;   K = 128; N = 128; nStride = 128; nOff = 0;   base = 832; }
  else if (bid < 2112) { src = W1; dst = W1_t;   K = 128; N = 512; nStride = 512; nOff = 0;   base = 1088; }
  else                 { src = W2; dst = W2_t;   K = 512; N = 128; nStride = 128; nOff = 0;   base = 2112; }
  int idx = (bid - base) * 256 + threadIdx.x;
  int k = idx % K;
  int rem = idx / K;
  int n = rem % N;
  int d = rem / N;
  dst[((size_t)d * nStride + nOff + n) * K + k] =
      f2bf(src[((size_t)d * K + k) * N + n] * scale);
}

// ---------------------------------------------------------------- embed
__global__ __launch_bounds__(256) void embed_kernel(
    const float* __restrict__ x_num, const float* __restrict__ W_numtok,
    const float* __restrict__ b_numtok, const float* __restrict__ E_cat,
    const float* __restrict__ b_cattok, const float* __restrict__ mask_tok,
    const float* __restrict__ random_prob, const float* __restrict__ rand_num,
    const float* __restrict__ rand_cat, const int* __restrict__ x_cat,
    const int* __restrict__ mask_num, const int* __restrict__ mask_cat,
    const float* __restrict__ pe, unsigned short* __restrict__ X)
{
  int token = blockIdx.x * 2 + (threadIdx.x >> 7);
  int e = threadIdx.x & 127;
  int b = token >> 7, f = token & 127;
  float v;
  if (f < cNN) {
    v = x_num[b * cNN + f] * W_numtok[f * cE + e] + b_numtok[f * cE + e];
  } else {
    int c = f - cNN;
    int idx = x_cat[b * cNC + c];
    v = E_cat[(c * cMC + idx) * cE + e] + b_cattok[c * cE + e];
  }
  float rp = random_prob[b];
  bool mn = mask_num[b * cF + f] != 0;
  bool mc = mask_cat[b * cF + f] != 0;
  if (rp < 0.8f) {
    if (!mn || !mc) v = mask_tok[e];
  } else if (rp < 0.9f) {
    if (!mn) v = rand_num[(b * cF + f) * cE + e];
    if (!mc) v = rand_cat[(b * cF + f) * cE + e];
  }
  v += pe[f * cE + e];
  X[(size_t)token * cE + e] = f2bf(v);
}

// ---------------------------------------------------------------- kernel A
// grid = (b, head-pair). Wq pre-scaled by 0.25*log2e -> softmax via exp2.
// s_setprio(1) wraps the MFMA clusters (waves are phase-independent here).
__global__ __launch_bounds__(512, 2) void qkv_attn_kernel(
    const unsigned short* __restrict__ X, const unsigned short* __restrict__ Wt,
    unsigned short* __restrict__ O)
{
  __shared__ unsigned short Qs[128 * 32];    // 8KB, chunk c^(row&3)
  __shared__ unsigned short Ks[128 * 32];    // 8KB
  __shared__ unsigned short Vt[2 * 16 * 128];// 8KB, [lh][dh][g] swz(g>>3,dh)
  __shared__ unsigned short Ws[96 * 128];    // 24KB staged QKV weights
  __shared__ unsigned short PX[8 * 2048];    // 32KB: per-wave X rows, then P strips
  const int tid = threadIdx.x;
  const int b = blockIdx.x >> 2, hp = blockIdx.x & 3;
  const int w = tid >> 6, l = tid & 63, hq = l >> 4, l15 = l & 15;
  const unsigned short* Xg = X + (size_t)b * 128 * 128;

  // ---- stage: per-wave X rows (16x128 swizzled) + block-wide weight slice
#pragma unroll
  for (int r = 0; r < 4; ++r) {
    int row16 = r * 4 + (l >> 4);
    int cl = l & 15;
    int sc = (cl & 8) | ((cl & 7) ^ (row16 & 7));
    GLD16(Xg + (w * 16 + row16) * 128 + sc * 8, &PX[w * 2048 + r * 512]);
  }
#pragma unroll
  for (int u = 0; u < 3; ++u) {
    int lr = u * 32 + (tid >> 4);
    int cl = tid & 15;
    int sc = (cl & 8) | ((cl & 7) ^ (lr & 7));
    int ng = (lr >> 5) * 128 + hp * 32 + (lr & 31);
    GLD16(Wt + ng * 128 + sc * 8, &Ws[u * 4096 + (w * 64) * 8]);
  }
  __syncthreads();

  // ---- QKV: wave w owns rows w*16..+15; 6 col-tiles (Q0 Q1 K0 K1 V0 V1)
  {
    f32x4 acc[6] = {};
    __builtin_amdgcn_s_setprio(1);
#pragma unroll
    for (int s = 0; s < 4; ++s) {
      int cd = s * 4 + hq;
      int cr = (cd & 8) | ((cd & 7) ^ (l15 & 7));
      bf16x8 af = *(const bf16x8*)&PX[w * 2048 + l15 * 128 + cr * 8];
#pragma unroll
      for (int j = 0; j < 6; ++j) {
        int ln = (j >> 1) * 32 + (j & 1) * 16 + l15;
        int cr2 = (cd & 8) | ((cd & 7) ^ (ln & 7));
        bf16x8 bw = *(const bf16x8*)&Ws[ln * 128 + cr2 * 8];
        acc[j] = __builtin_amdgcn_mfma_f32_16x16x32_bf16(af, bw, acc[j], 0, 0, 0);
      }
    }
    __builtin_amdgcn_s_setprio(0);
    const int r0 = w * 16 + hq * 4;
#pragma unroll
    for (int j = 0; j < 6; ++j) {
      if (j < 4) {
        unsigned short* dst = (j < 2) ? Qs : Ks;
        int col = (j & 1) * 16 + l15;
#pragma unroll
        for (int r = 0; r < 4; ++r) {
          int row2 = r0 + r;
          dst[row2 * 32 + ((col >> 3) ^ (row2 & 3)) * 8 + (col & 7)] = f2bf(acc[j][r]);
        }
      } else {
        int lh = j - 4, dh = l15;
#pragma unroll
        for (int rp = 0; rp < 2; ++rp) {
          int g = r0 + rp * 2;
          unsigned pk = packbf(acc[j][rp * 2], acc[j][rp * 2 + 1]);
          *(unsigned*)&Vt[lh * 2048 + dh * 128 + ((g >> 3) ^ (dh & 7)) * 8 + (g & 7)] = pk;
        }
      }
    }
  }
  __syncthreads();

  // ---- attention: 4 waves per head (lh = w>>2), each wave 2 row-groups of 16
  {
    const int lh = w >> 2, wq = w & 3, h = hp * 2 + lh;
    const bf16x8 zfrag = {0, 0, 0, 0, 0, 0, 0, 0};
#pragma unroll 1
    for (int ft2 = 0; ft2 < 2; ++ft2) {
      int ft = wq * 2 + ft2;
      int f = ft * 16 + l15;
      bf16x8 bq = zfrag;
      if (hq < 2) bq = *(const bf16x8*)&Qs[f * 32 + ((lh * 2 + hq) ^ (f & 3)) * 8];
      f32x4 sa[8];
      __builtin_amdgcn_s_setprio(1);
#pragma unroll
      for (int gt = 0; gt < 8; ++gt) {
        int g = gt * 16 + l15;
        bf16x8 ak = zfrag;
        if (hq < 2) ak = *(const bf16x8*)&Ks[g * 32 + ((lh * 2 + hq) ^ (g & 3)) * 8];
        f32x4 z = {0.f, 0.f, 0.f, 0.f};
        sa[gt] = __builtin_amdgcn_mfma_f32_16x16x32_bf16(ak, bq, z, 0, 0, 0);
      }
      __builtin_amdgcn_s_setprio(0);
      // scores are pre-scaled by 0.25*log2e -> base-2 softmax == exp softmax
      float mx = -3.0e38f;
#pragma unroll
      for (int gt = 0; gt < 8; ++gt)
#pragma unroll
        for (int r = 0; r < 4; ++r) mx = fmaxf(mx, sa[gt][r]);
      mx = fmaxf(mx, __shfl_xor(mx, 16));
      mx = fmaxf(mx, __shfl_xor(mx, 32));
      float sum = 0.f;
#pragma unroll
      for (int gt = 0; gt < 8; ++gt)
#pragma unroll
        for (int r = 0; r < 4; ++r) {
          float e = exp2f(sa[gt][r] - mx);
          sa[gt][r] = e;
          sum += e;
        }
      sum += __shfl_xor(sum, 16);
      sum += __shfl_xor(sum, 32);
      float inv = 1.f / sum;
      f32x4 oa = {0.f, 0.f, 0.f, 0.f};
#pragma unroll
      for (int gh = 0; gh < 2; ++gh) {
#pragma unroll
        for (int g2 = 0; g2 < 4; ++g2) {
          int gt = gh * 4 + g2;
#pragma unroll
          for (int rp = 0; rp < 2; ++rp) {
            unsigned pk = packbf(sa[gt][rp * 2], sa[gt][rp * 2 + 1]);
            int gl = g2 * 16 + hq * 4 + rp * 2;
            *(unsigned*)&PX[w * 2048 + l15 * 64 + ((gl >> 3) ^ (l15 & 7)) * 8 + (gl & 7)] = pk;
          }
        }
        asm volatile("s_waitcnt lgkmcnt(0)" ::: "memory");
        __builtin_amdgcn_sched_barrier(0);
        __builtin_amdgcn_s_setprio(1);
#pragma unroll
        for (int s2 = 0; s2 < 2; ++s2) {
          bf16x8 pa = *(const bf16x8*)&PX[w * 2048 + l15 * 64 + ((s2 * 4 + hq) ^ (l15 & 7)) * 8];
          int cgv = gh * 8 + s2 * 4 + hq;
          bf16x8 bv = *(const bf16x8*)&Vt[lh * 2048 + l15 * 128 + swz(cgv, l15) * 8];
          oa = __builtin_amdgcn_mfma_f32_16x16x32_bf16(pa, bv, oa, 0, 0, 0);
        }
        __builtin_amdgcn_s_setprio(0);
      }
#pragma unroll
      for (int r = 0; r < 4; ++r) {
        int fo = ft * 16 + hq * 4 + r;
        O[((size_t)b * 128 + fo) * 128 + h * 16 + l15] =
            f2bf(oa[r] * __shfl(inv, hq * 4 + r));
      }
    }
  }
}

// ---------------------------------------------------------------- kernel B
// unchanged r16 control: double-buffered weight LDS, register-resident rows.
__global__ __launch_bounds__(512, 2) void ffn_kernel(
    const unsigned short* __restrict__ O, unsigned short* __restrict__ X,
    const unsigned short* __restrict__ Wo_d, const unsigned short* __restrict__ W1_d,
    const unsigned short* __restrict__ W2_d,
    const float* __restrict__ g1, const float* __restrict__ be1,
    const float* __restrict__ g2, const float* __restrict__ be2,
    const float* __restrict__ b1d, const float* __restrict__ b2d)
{
  __shared__ unsigned short strip[8][1024];   // 2KB per wave (16KB)
  __shared__ unsigned short Ws[32768];        // 64KB: W1buf0|W1buf1|W2buf0|W2buf1
  const int w = threadIdx.x >> 6, l = threadIdx.x & 63;
  const int hq = l >> 4, l15 = l & 15;
  const size_t rbase = ((size_t)blockIdx.x * 8 + w) * 16 * 128;  // wave's 16 rows
  unsigned short* st = strip[w];

  // ---- stage Wo (128x128 = 32KB) into Ws[0..16383]
#pragma unroll
  for (int u = 0; u < 4; ++u) {
    int i = w * 4 + u;
    int n = i * 4 + (l >> 4);
    int q = l & 15;
    int cc = (q & 8) | ((q & 7) ^ (n & 7));
    GLD16(Wo_d + n * 128 + cc * 8, &Ws[i * 512]);
  }
  __syncthreads();                                  // Ws(Wo) ready

  // ================ Wo: A = O row-frags (global, own rows), B from Ws
  f32x4 acc[8] = {};
#pragma unroll
  for (int s = 0; s < 4; ++s) {
    bf16x8 of = *(const bf16x8*)&O[rbase + (size_t)l15 * 128 + s * 32 + hq * 8];
    int cd = s * 4 + hq;
#pragma unroll
    for (int j = 0; j < 8; ++j) {
      int n = j * 16 + l15;
      bf16x8 bw = *(const bf16x8*)&Ws[n * 128 + swz(cd, n) * 8];
      acc[j] = __builtin_amdgcn_mfma_f32_16x16x32_bf16(of, bw, acc[j], 0, 0, 0);
    }
  }
  __syncthreads();                                  // Wo readers done
  // ---- prefetch W1(0)->buf0, W2(0)->buf0 (lands at FFN loop's first barrier)
#pragma unroll
  for (int u = 0; u < 2; ++u) {
    int i = w * 2 + u;
    {
      int nl = i * 4 + (l >> 4);
      int q = l & 15;
      int cc = (q & 8) | ((q & 7) ^ (nl & 7));
      GLD16(W1_d + (size_t)nl * 128 + cc * 8, &Ws[i * 512]);
    }
    {
      int n = i * 8 + (l >> 3);
      int q = l & 7;
      int kc = q ^ (n & 7);
      GLD16(W2_d + (size_t)n * 512 + kc * 8, &Ws[16384 + i * 512]);
    }
  }

  // ================ LN1, two-pass over 64-col halves (strip = [16][64])
  bf16x8 xp[4], xv[4];
  {
    float sm = 0.f, sq = 0.f;
#pragma unroll
    for (int h = 0; h < 2; ++h) {
#pragma unroll
      for (int j4 = 0; j4 < 4; ++j4) {
        int j = h * 4 + j4;
#pragma unroll
        for (int r = 0; r < 4; ++r) {
          int R = hq * 4 + r, cc = j4 * 2 + (l15 >> 3);
          st[R * 64 + (cc ^ (R & 7)) * 8 + (l15 & 7)] = f2bf(acc[j][r]);
        }
      }
      asm volatile("s_waitcnt lgkmcnt(0)" ::: "memory");
      __builtin_amdgcn_sched_barrier(0);
#pragma unroll
      for (int sp = 0; sp < 2; ++sp) {
        int s = h * 2 + sp;
        bf16x8 av = *(const bf16x8*)&st[l15 * 64 + ((sp * 4 + hq) ^ (l15 & 7)) * 8];
        xv[s] = *(const bf16x8*)&X[rbase + (size_t)l15 * 128 + s * 32 + hq * 8];
#pragma unroll
        for (int u = 0; u < 8; ++u) {
          float v = bf2f((unsigned short)av[u]) + bf2f((unsigned short)xv[s][u]);
          sm += v; sq += v * v;
        }
      }
    }
    sm += __shfl_xor(sm, 16); sm += __shfl_xor(sm, 32);
    sq += __shfl_xor(sq, 16); sq += __shfl_xor(sq, 32);
    float mu = sm * (1.f / 128.f);
    float iv = rsqrtf(sq * (1.f / 128.f) - mu * mu + 1e-5f);
    // pass 2: normalize. st currently holds half 1 -> do h=1 first, then h=0.
#pragma unroll
    for (int hh = 0; hh < 2; ++hh) {
      int h = 1 - hh;
      if (hh == 1) {     // re-transpose half 0
#pragma unroll
        for (int j4 = 0; j4 < 4; ++j4)
#pragma unroll
          for (int r = 0; r < 4; ++r) {
            int R = hq * 4 + r, cc = j4 * 2 + (l15 >> 3);
            st[R * 64 + (cc ^ (R & 7)) * 8 + (l15 & 7)] = f2bf(acc[j4][r]);
          }
        asm volatile("s_waitcnt lgkmcnt(0)" ::: "memory");
        __builtin_amdgcn_sched_barrier(0);
      }
#pragma unroll
      for (int sp = 0; sp < 2; ++sp) {
        int s = h * 2 + sp;
        bf16x8 av = *(const bf16x8*)&st[l15 * 64 + ((sp * 4 + hq) ^ (l15 & 7)) * 8];
        const float* gp = g1 + s * 32 + hq * 8;
        const float* bp = be1 + s * 32 + hq * 8;
#pragma unroll
        for (int u = 0; u < 8; ++u) {
          float v = bf2f((unsigned short)av[u]) + bf2f((unsigned short)xv[s][u]);
          xp[s][u] = (short)f2bf((v - mu) * iv * gp[u] + bp[u]);
        }
      }
    }
  }

  // ================ FFN: 8 chunks of 64 H-cols, double-buffered weights,
  // ONE barrier per chunk; staging(nc+1) overlaps compute(nc).
  f32x4 acc2[8] = {};
  int p = 0;
#pragma unroll 1
  for (int nc = 0; nc < 8; ++nc) {
    __syncthreads();                 // buf[p] ready; all waves done with buf[p^1]
    if (nc < 7) {                    // stage chunk nc+1 into buf[p^1]
#pragma unroll
      for (int u = 0; u < 2; ++u) {
        int i = w * 2 + u;
        int nl = i * 4 + (l >> 4);
        int q = l & 15;
        int cc = (q & 8) | ((q & 7) ^ (nl & 7));
        GLD16(W1_d + (size_t)((nc + 1) * 64 + nl) * 128 + cc * 8,
              &Ws[(p ^ 1) * 8192 + i * 512]);
        int n = i * 8 + (l >> 3);
        int q2 = l & 7;
        int kc = q2 ^ (n & 7);
        GLD16(W2_d + (size_t)n * 512 + (nc + 1) * 64 + kc * 8,
              &Ws[16384 + (p ^ 1) * 8192 + i * 512]);
      }
    }
    const unsigned short* W1p = Ws + p * 8192;
    const unsigned short* W2p = Ws + 16384 + p * 8192;
    // FFN1 chunk: a1[4] -> 4 independent MFMA chains
    f32x4 a1[4] = {};
#pragma unroll
    for (int s = 0; s < 4; ++s) {
      int cd = s * 4 + hq;
#pragma unroll
      for (int jj = 0; jj < 4; ++jj) {
        int nl = jj * 16 + l15;
        bf16x8 bw = *(const bf16x8*)&W1p[nl * 128 + swz(cd, nl) * 8];
        a1[jj] = __builtin_amdgcn_mfma_f32_16x16x32_bf16(xp[s], bw, a1[jj], 0, 0, 0);
      }
    }
#pragma unroll
    for (int jj = 0; jj < 4; ++jj) {
      float bv = b1d[nc * 64 + jj * 16 + l15];
#pragma unroll
      for (int r = 0; r < 4; ++r) {
        int R = hq * 4 + r, cc = jj * 2 + (l15 >> 3);
        st[R * 64 + (cc ^ (R & 7)) * 8 + (l15 & 7)] = f2bf(fmaxf(a1[jj][r] + bv, 0.f));
      }
    }
    asm volatile("s_waitcnt lgkmcnt(0)" ::: "memory");
    __builtin_amdgcn_sched_barrier(0);
    bf16x8 hf[2];
#pragma unroll
    for (int sl = 0; sl < 2; ++sl)
      hf[sl] = *(const bf16x8*)&st[l15 * 64 + ((sl * 4 + hq) ^ (l15 & 7)) * 8];
    // FFN2 chunk from W2 buffer
#pragma unroll
    for (int sl = 0; sl < 2; ++sl) {
      int kc = sl * 4 + hq;
#pragma unroll
      for (int j = 0; j < 8; ++j) {
        int n = j * 16 + l15;
        bf16x8 bw = *(const bf16x8*)&W2p[n * 64 + (kc ^ (n & 7)) * 8];
        acc2[j] = __builtin_amdgcn_mfma_f32_16x16x32_bf16(hf[sl], bw, acc2[j], 0, 0, 0);
      }
    }
    p ^= 1;
  }

  // ================ + b2, two-pass LN2 (residual = xp), store X
  {
    float sm = 0.f, sq = 0.f;
#pragma unroll
    for (int h = 0; h < 2; ++h) {
#pragma unroll
      for (int j4 = 0; j4 < 4; ++j4) {
        int j = h * 4 + j4;
        float bv = b2d[j * 16 + l15];
#pragma unroll
        for (int r = 0; r < 4; ++r) {
          int R = hq * 4 + r, cc = j4 * 2 + (l15 >> 3);
          st[R * 64 + (cc ^ (R & 7)) * 8 + (l15 & 7)] = f2bf(acc2[j][r] + bv);
        }
      }
      asm volatile("s_waitcnt lgkmcnt(0)" ::: "memory");
      __builtin_amdgcn_sched_barrier(0);
#pragma unroll
      for (int sp = 0; sp < 2; ++sp) {
        int s = h * 2 + sp;
        bf16x8 av = *(const bf16x8*)&st[l15 * 64 + ((sp * 4 + hq) ^ (l15 & 7)) * 8];
#pragma unroll
        for (int u = 0; u < 8; ++u) {
          float v = bf2f((unsigned short)av[u]) + bf2f((unsigned short)xp[s][u]);
          sm += v; sq += v * v;
        }
      }
    }
    sm += __shfl_xor(sm, 16); sm += __shfl_xor(sm, 32);
    sq += __shfl_xor(sq, 16); sq += __shfl_xor(sq, 32);
    float mu = sm * (1.f / 128.f);
    float iv = rsqrtf(sq * (1.f / 128.f) - mu * mu + 1e-5f);
#pragma unroll
    for (int hh = 0; hh < 2; ++hh) {
      int h = 1 - hh;
      if (hh == 1) {     // re-transpose half 0 (+bias)
#pragma unroll
        for (int j4 = 0; j4 < 4; ++j4) {
          float bv = b2d[j4 * 16 + l15];
#pragma unroll
          for (int r = 0; r < 4; ++r) {
            int R = hq * 4 + r, cc = j4 * 2 + (l15 >> 3);
            st[R * 64 + (cc ^ (R & 7)) * 8 + (l15 & 7)] = f2bf(acc2[j4][r] + bv);
          }
        }
        asm volatile("s_waitcnt lgkmcnt(0)" ::: "memory");
        __builtin_amdgcn_sched_barrier(0);
      }
#pragma unroll
      for (int sp = 0; sp < 2; ++sp) {
        int s = h * 2 + sp;
        bf16x8 av = *(const bf16x8*)&st[l15 * 64 + ((sp * 4 + hq) ^ (l15 & 7)) * 8];
        const float* gp = g2 + s * 32 + hq * 8;
        const float* bp = be2 + s * 32 + hq * 8;
        bf16x8 ov;
#pragma unroll
        for (int u2 = 0; u2 < 4; ++u2) {
          float v0 = bf2f((unsigned short)av[u2 * 2]) + bf2f((unsigned short)xp[s][u2 * 2]);
          float v1 = bf2f((unsigned short)av[u2 * 2 + 1]) + bf2f((unsigned short)xp[s][u2 * 2 + 1]);
          float o0 = (v0 - mu) * iv * gp[u2 * 2] + bp[u2 * 2];
          float o1 = (v1 - mu) * iv * gp[u2 * 2 + 1] + bp[u2 * 2 + 1];
          ((unsigned*)&ov)[u2] = packbf(o0, o1);
        }
        *(bf16x8*)&X[rbase + (size_t)l15 * 128 + s * 32 + hq * 8] = ov;
      }
    }
  }
}

// ---------------------------------------------------------------- decoders
__global__ __launch_bounds__(64) void decode_kernel(
    const unsigned short* __restrict__ X, const float* __restrict__ Wdn,
    const float* __restrict__ bdn, const float* __restrict__ Wdc,
    const float* __restrict__ bdc, const int* __restrict__ pin,
    const int* __restrict__ pic, const int* __restrict__ cards,
    float* __restrict__ out)
{
  __shared__ float tokc[128];
  int b = blockIdx.x, t = threadIdx.x;
  int idn = pin[b];
  const unsigned short* xr = X + (size_t)(b * cF + idn) * cE;
  float p = bf2f(xr[t]) * Wdn[idn * cE + t] + bf2f(xr[t + 64]) * Wdn[idn * cE + t + 64];
#pragma unroll
  for (int off = 32; off; off >>= 1) p += __shfl_xor(p, off);
  if (t == 0) out[b] = p + bdn[idn];
  int idc = pic[b];
  const unsigned short* xc = X + (size_t)(b * cF + idc) * cE;
  tokc[t] = bf2f(xc[t]);
  tokc[t + 64] = bf2f(xc[t + 64]);
  __syncthreads();
  float acc = bdc[idc * cMC + t];
  const float* wv = Wdc + (size_t)idc * cE * cMC + t;
  for (int e2 = 0; e2 < 128; ++e2) acc += tokc[e2] * wv[(size_t)e2 * cMC];
  int card = cards[idc];
  out[cB + b * cMC + t] = (t >= card) ? -100.f : acc;
}

// ---------------------------------------------------------------- launch
extern "C" void kernel_launch(void* const* d_in, const int* in_sizes, int n_in,
                              void* d_out, int out_size, void* d_ws, size_t ws_size,
                              hipStream_t stream)
{
  const float* x_num    = (const float*)d_in[0];
  const float* W_numtok = (const float*)d_in[1];
  const float* b_numtok = (const float*)d_in[2];
  const float* E_cat    = (const float*)d_in[3];
  const float* b_cattok = (const float*)d_in[4];
  const float* mask_tok = (const float*)d_in[5];
  const float* random_prob = (const float*)d_in[6];
  const float* rand_num = (const float*)d_in[7];
  const float* rand_cat = (const float*)d_in[8];
  const float* Wq   = (const float*)d_in[9];
  const float* Wk   = (const float*)d_in[10];
  const float* Wv   = (const float*)d_in[11];
  const float* Wo   = (const float*)d_in[12];
  const float* ln1g = (const float*)d_in[13];
  const float* ln1b = (const float*)d_in[14];
  const float* W1   = (const float*)d_in[15];
  const float* b1   = (const float*)d_in[16];
  const float* W2   = (const float*)d_in[17];
  const float* b2   = (const float*)d_in[18];
  const float* ln2g = (const float*)d_in[19];
  const float* ln2b = (const float*)d_in[20];
  const float* Wdn  = (const float*)d_in[21];
  const float* bdn  = (const float*)d_in[22];
  const float* Wdc  = (const float*)d_in[23];
  const float* bdc  = (const float*)d_in[24];
  const int* x_cat    = (const int*)d_in[25];
  const int* mask_num = (const int*)d_in[26];
  const int* mask_cat = (const int*)d_in[27];
  const int* pin      = (const int*)d_in[28];
  const int* pic      = (const int*)d_in[29];
  const int* cards    = (const int*)d_in[30];
  float* out = (float*)d_out;

  unsigned short* Wqkv_t = (unsigned short*)d_ws;           // 4*384*128
  unsigned short* Wo_t   = Wqkv_t + (size_t)4 * 384 * 128;  // 4*128*128
  unsigned short* W1_t   = Wo_t + (size_t)4 * 128 * 128;    // 4*512*128
  unsigned short* W2_t   = W1_t + (size_t)4 * 512 * 128;    // 4*128*512
  float* pe = (float*)(W2_t + (size_t)4 * 128 * 512);       // 16384 f32
  unsigned short* Xact = (unsigned short*)(pe + 16384);     // TOK*128
  unsigned short* Oact = Xact + (size_t)TOK * 128;          // TOK*128

  setup_kernel<<<3136, 256, 0, stream>>>(Wq, Wk, Wv, Wo, W1, W2,
      Wqkv_t, Wo_t, W1_t, W2_t, pe);

  embed_kernel<<<TOK / 2, 256, 0, stream>>>(x_num, W_numtok, b_numtok, E_cat,
      b_cattok, mask_tok, random_prob, rand_num, rand_cat, x_cat, mask_num,
      mask_cat, pe, Xact);

  for (int d = 0; d < cD; ++d) {
    qkv_attn_kernel<<<cB * 4, 512, 0, stream>>>(
        Xact, Wqkv_t + (size_t)d * 384 * 128, Oact);
    ffn_kernel<<<TOK / 128, 512, 0, stream>>>(
        Oact, Xact, Wo_t + (size_t)d * 128 * 128,
        W1_t + (size_t)d * 512 * 128, W2_t + (size_t)d * 128 * 512,
        ln1g + d * cE, ln1b + d * cE, ln2g + d * cE, ln2b + d * cE,
        b1 + d * cFF, b2 + d * cE);
  }

  decode_kernel<<<cB, 64, 0, stream>>>(Xact, Wdn, bdn, Wdc, bdc, pin, pic, cards, out);
}

// Round 18
// 371.692 us; speedup vs baseline: 1.0131x; 1.0131x over previous
//
#include <hip/hip_runtime.h>
#include <hip/hip_bf16.h>

typedef __attribute__((ext_vector_type(8))) short bf16x8;
typedef __attribute__((ext_vector_type(4))) float f32x4;

constexpr int cB = 512, cNN = 96, cNC = 32, cF = 128, cE = 128,
              cH = 8, cDH = 16, cFF = 512, cD = 4, cMC = 64;
constexpr int TOK = cB * cF;

__device__ __forceinline__ float bf2f(unsigned short u) {
  union { float f; unsigned i; } v; v.i = ((unsigned)u) << 16; return v.f;
}
__device__ __forceinline__ unsigned short f2bf(float f) {
  __hip_bfloat16 h = __float2bfloat16(f);
  return *reinterpret_cast<unsigned short*>(&h);
}
__device__ __forceinline__ unsigned packbf(float a, float b) {
  __hip_bfloat162 h = __float22bfloat162_rn(make_float2(a, b));
  return *reinterpret_cast<unsigned*>(&h);
}
// XOR-swizzle of 16B-chunk index within aligned 8-chunk groups (involution)
__device__ __forceinline__ int swz(int c, int r) {
  return (c & ~7) | ((c & 7) ^ (r & 7));
}

#define GLD16(g, l) __builtin_amdgcn_global_load_lds( \
    (const __attribute__((address_space(1))) void*)(g), \
    (__attribute__((address_space(3))) void*)(l), 16, 0, 0)

// ---------------------------------------------------------------- setup
// one launch: pe table + all 6 weight packs, range-dispatched on blockIdx.
// Wq is scaled by 0.25*log2(e) so attn softmax can use exp2 directly.
__global__ __launch_bounds__(256) void setup_kernel(
    const float* __restrict__ Wq, const float* __restrict__ Wk,
    const float* __restrict__ Wv, const float* __restrict__ Wo,
    const float* __restrict__ W1, const float* __restrict__ W2,
    unsigned short* __restrict__ Wqkv_t, unsigned short* __restrict__ Wo_t,
    unsigned short* __restrict__ W1_t, unsigned short* __restrict__ W2_t,
    float* __restrict__ pe)
{
  int bid = blockIdx.x;
  if (bid < 64) {
    int idx = bid * 256 + threadIdx.x;              // 128*128
    int f = idx >> 7, e = idx & 127;
    int i = e >> 1;
    float ang = (float)f * expf(-(float)(2 * i) * 0.07195578415606394f);
    pe[idx] = (e & 1) ? cosf(ang) : sinf(ang);
    return;
  }
  const float* src; unsigned short* dst;
  int K, N, nStride, nOff, base;
  float scale = 1.0f;
  if (bid < 320)       { src = Wq; dst = Wqkv_t; K = 128; N = 128; nStride = 384; nOff = 0;   base = 64;
                         scale = 0.3606737602222409f; }   // 0.25 * log2(e)
  else if (bid < 576)  { src = Wk; dst = Wqkv_t; K = 128; N = 128; nStride = 384; nOff = 128; base = 320; }
  else if (bid < 832)  { src = Wv; dst = Wqkv_t; K = 128; N = 128; nStride = 384; nOff = 256; base = 576; }
  else if (bid < 1088) { src = Wo; dst = Wo_t;   K = 128; N = 128; nStride = 128; nOff = 0;   base = 832; }
  else if (bid < 2112) { src = W1; dst = W1_t;   K = 128; N = 512; nStride = 512; nOff = 0;   base = 1088; }
  else                 { src = W2; dst = W2_t;   K = 512; N = 128; nStride = 128; nOff = 0;   base = 2112; }
  int idx = (bid - base) * 256 + threadIdx.x;
  int k = idx % K;
  int rem = idx / K;
  int n = rem % N;
  int d = rem / N;
  dst[((size_t)d * nStride + nOff + n) * K + k] =
      f2bf(src[((size_t)d * K + k) * N + n] * scale);
}

// ---------------------------------------------------------------- embed
__global__ __launch_bounds__(256) void embed_kernel(
    const float* __restrict__ x_num, const float* __restrict__ W_numtok,
    const float* __restrict__ b_numtok, const float* __restrict__ E_cat,
    const float* __restrict__ b_cattok, const float* __restrict__ mask_tok,
    const float* __restrict__ random_prob, const float* __restrict__ rand_num,
    const float* __restrict__ rand_cat, const int* __restrict__ x_cat,
    const int* __restrict__ mask_num, const int* __restrict__ mask_cat,
    const float* __restrict__ pe, unsigned short* __restrict__ X)
{
  int token = blockIdx.x * 2 + (threadIdx.x >> 7);
  int e = threadIdx.x & 127;
  int b = token >> 7, f = token & 127;
  float v;
  if (f < cNN) {
    v = x_num[b * cNN + f] * W_numtok[f * cE + e] + b_numtok[f * cE + e];
  } else {
    int c = f - cNN;
    int idx = x_cat[b * cNC + c];
    v = E_cat[(c * cMC + idx) * cE + e] + b_cattok[c * cE + e];
  }
  float rp = random_prob[b];
  bool mn = mask_num[b * cF + f] != 0;
  bool mc = mask_cat[b * cF + f] != 0;
  if (rp < 0.8f) {
    if (!mn || !mc) v = mask_tok[e];
  } else if (rp < 0.9f) {
    if (!mn) v = rand_num[(b * cF + f) * cE + e];
    if (!mc) v = rand_cat[(b * cF + f) * cE + e];
  }
  v += pe[f * cE + e];
  X[(size_t)token * cE + e] = f2bf(v);
}

// ---------------------------------------------------------------- kernel A
// grid = (b, head-pair). Wq pre-scaled by 0.25*log2e -> softmax via exp2.
// NO setprio (r17 showed it regresses this kernel: lockstep phases, m190).
__global__ __launch_bounds__(512, 2) void qkv_attn_kernel(
    const unsigned short* __restrict__ X, const unsigned short* __restrict__ Wt,
    unsigned short* __restrict__ O)
{
  __shared__ unsigned short Qs[128 * 32];    // 8KB, chunk c^(row&3)
  __shared__ unsigned short Ks[128 * 32];    // 8KB
  __shared__ unsigned short Vt[2 * 16 * 128];// 8KB, [lh][dh][g] swz(g>>3,dh)
  __shared__ unsigned short Ws[96 * 128];    // 24KB staged QKV weights
  __shared__ unsigned short PX[8 * 2048];    // 32KB: per-wave X rows, then P strips
  const int tid = threadIdx.x;
  const int b = blockIdx.x >> 2, hp = blockIdx.x & 3;
  const int w = tid >> 6, l = tid & 63, hq = l >> 4, l15 = l & 15;
  const unsigned short* Xg = X + (size_t)b * 128 * 128;

  // ---- stage: per-wave X rows (16x128 swizzled) + block-wide weight slice
#pragma unroll
  for (int r = 0; r < 4; ++r) {
    int row16 = r * 4 + (l >> 4);
    int cl = l & 15;
    int sc = (cl & 8) | ((cl & 7) ^ (row16 & 7));
    GLD16(Xg + (w * 16 + row16) * 128 + sc * 8, &PX[w * 2048 + r * 512]);
  }
#pragma unroll
  for (int u = 0; u < 3; ++u) {
    int lr = u * 32 + (tid >> 4);
    int cl = tid & 15;
    int sc = (cl & 8) | ((cl & 7) ^ (lr & 7));
    int ng = (lr >> 5) * 128 + hp * 32 + (lr & 31);
    GLD16(Wt + ng * 128 + sc * 8, &Ws[u * 4096 + (w * 64) * 8]);
  }
  __syncthreads();

  // ---- QKV: wave w owns rows w*16..+15; 6 col-tiles (Q0 Q1 K0 K1 V0 V1)
  {
    f32x4 acc[6] = {};
#pragma unroll
    for (int s = 0; s < 4; ++s) {
      int cd = s * 4 + hq;
      int cr = (cd & 8) | ((cd & 7) ^ (l15 & 7));
      bf16x8 af = *(const bf16x8*)&PX[w * 2048 + l15 * 128 + cr * 8];
#pragma unroll
      for (int j = 0; j < 6; ++j) {
        int ln = (j >> 1) * 32 + (j & 1) * 16 + l15;
        int cr2 = (cd & 8) | ((cd & 7) ^ (ln & 7));
        bf16x8 bw = *(const bf16x8*)&Ws[ln * 128 + cr2 * 8];
        acc[j] = __builtin_amdgcn_mfma_f32_16x16x32_bf16(af, bw, acc[j], 0, 0, 0);
      }
    }
    const int r0 = w * 16 + hq * 4;
#pragma unroll
    for (int j = 0; j < 6; ++j) {
      if (j < 4) {
        unsigned short* dst = (j < 2) ? Qs : Ks;
        int col = (j & 1) * 16 + l15;
#pragma unroll
        for (int r = 0; r < 4; ++r) {
          int row2 = r0 + r;
          dst[row2 * 32 + ((col >> 3) ^ (row2 & 3)) * 8 + (col & 7)] = f2bf(acc[j][r]);
        }
      } else {
        int lh = j - 4, dh = l15;
#pragma unroll
        for (int rp = 0; rp < 2; ++rp) {
          int g = r0 + rp * 2;
          unsigned pk = packbf(acc[j][rp * 2], acc[j][rp * 2 + 1]);
          *(unsigned*)&Vt[lh * 2048 + dh * 128 + ((g >> 3) ^ (dh & 7)) * 8 + (g & 7)] = pk;
        }
      }
    }
  }
  __syncthreads();

  // ---- attention: 4 waves per head (lh = w>>2), each wave 2 row-groups of 16
  {
    const int lh = w >> 2, wq = w & 3, h = hp * 2 + lh;
    const bf16x8 zfrag = {0, 0, 0, 0, 0, 0, 0, 0};
#pragma unroll 1
    for (int ft2 = 0; ft2 < 2; ++ft2) {
      int ft = wq * 2 + ft2;
      int f = ft * 16 + l15;
      bf16x8 bq = zfrag;
      if (hq < 2) bq = *(const bf16x8*)&Qs[f * 32 + ((lh * 2 + hq) ^ (f & 3)) * 8];
      f32x4 sa[8];
#pragma unroll
      for (int gt = 0; gt < 8; ++gt) {
        int g = gt * 16 + l15;
        bf16x8 ak = zfrag;
        if (hq < 2) ak = *(const bf16x8*)&Ks[g * 32 + ((lh * 2 + hq) ^ (g & 3)) * 8];
        f32x4 z = {0.f, 0.f, 0.f, 0.f};
        sa[gt] = __builtin_amdgcn_mfma_f32_16x16x32_bf16(ak, bq, z, 0, 0, 0);
      }
      // scores are pre-scaled by 0.25*log2e -> base-2 softmax == exp softmax
      float mx = -3.0e38f;
#pragma unroll
      for (int gt = 0; gt < 8; ++gt)
#pragma unroll
        for (int r = 0; r < 4; ++r) mx = fmaxf(mx, sa[gt][r]);
      mx = fmaxf(mx, __shfl_xor(mx, 16));
      mx = fmaxf(mx, __shfl_xor(mx, 32));
      float sum = 0.f;
#pragma unroll
      for (int gt = 0; gt < 8; ++gt)
#pragma unroll
        for (int r = 0; r < 4; ++r) {
          float e = exp2f(sa[gt][r] - mx);
          sa[gt][r] = e;
          sum += e;
        }
      sum += __shfl_xor(sum, 16);
      sum += __shfl_xor(sum, 32);
      float inv = 1.f / sum;
      f32x4 oa = {0.f, 0.f, 0.f, 0.f};
#pragma unroll
      for (int gh = 0; gh < 2; ++gh) {
#pragma unroll
        for (int g2 = 0; g2 < 4; ++g2) {
          int gt = gh * 4 + g2;
#pragma unroll
          for (int rp = 0; rp < 2; ++rp) {
            unsigned pk = packbf(sa[gt][rp * 2], sa[gt][rp * 2 + 1]);
            int gl = g2 * 16 + hq * 4 + rp * 2;
            *(unsigned*)&PX[w * 2048 + l15 * 64 + ((gl >> 3) ^ (l15 & 7)) * 8 + (gl & 7)] = pk;
          }
        }
        asm volatile("s_waitcnt lgkmcnt(0)" ::: "memory");
        __builtin_amdgcn_sched_barrier(0);
#pragma unroll
        for (int s2 = 0; s2 < 2; ++s2) {
          bf16x8 pa = *(const bf16x8*)&PX[w * 2048 + l15 * 64 + ((s2 * 4 + hq) ^ (l15 & 7)) * 8];
          int cgv = gh * 8 + s2 * 4 + hq;
          bf16x8 bv = *(const bf16x8*)&Vt[lh * 2048 + l15 * 128 + swz(cgv, l15) * 8];
          oa = __builtin_amdgcn_mfma_f32_16x16x32_bf16(pa, bv, oa, 0, 0, 0);
        }
      }
#pragma unroll
      for (int r = 0; r < 4; ++r) {
        int fo = ft * 16 + hq * 4 + r;
        O[((size_t)b * 128 + fo) * 128 + h * 16 + l15] =
            f2bf(oa[r] * __shfl(inv, hq * 4 + r));
      }
    }
  }
}

// ---------------------------------------------------------------- kernel B
// unchanged r16 control: double-buffered weight LDS, register-resident rows.
__global__ __launch_bounds__(512, 2) void ffn_kernel(
    const unsigned short* __restrict__ O, unsigned short* __restrict__ X,
    const unsigned short* __restrict__ Wo_d, const unsigned short* __restrict__ W1_d,
    const unsigned short* __restrict__ W2_d,
    const float* __restrict__ g1, const float* __restrict__ be1,
    const float* __restrict__ g2, const float* __restrict__ be2,
    const float* __restrict__ b1d, const float* __restrict__ b2d)
{
  __shared__ unsigned short strip[8][1024];   // 2KB per wave (16KB)
  __shared__ unsigned short Ws[32768];        // 64KB: W1buf0|W1buf1|W2buf0|W2buf1
  const int w = threadIdx.x >> 6, l = threadIdx.x & 63;
  const int hq = l >> 4, l15 = l & 15;
  const size_t rbase = ((size_t)blockIdx.x * 8 + w) * 16 * 128;  // wave's 16 rows
  unsigned short* st = strip[w];

  // ---- stage Wo (128x128 = 32KB) into Ws[0..16383]
#pragma unroll
  for (int u = 0; u < 4; ++u) {
    int i = w * 4 + u;
    int n = i * 4 + (l >> 4);
    int q = l & 15;
    int cc = (q & 8) | ((q & 7) ^ (n & 7));
    GLD16(Wo_d + n * 128 + cc * 8, &Ws[i * 512]);
  }
  __syncthreads();                                  // Ws(Wo) ready

  // ================ Wo: A = O row-frags (global, own rows), B from Ws
  f32x4 acc[8] = {};
#pragma unroll
  for (int s = 0; s < 4; ++s) {
    bf16x8 of = *(const bf16x8*)&O[rbase + (size_t)l15 * 128 + s * 32 + hq * 8];
    int cd = s * 4 + hq;
#pragma unroll
    for (int j = 0; j < 8; ++j) {
      int n = j * 16 + l15;
      bf16x8 bw = *(const bf16x8*)&Ws[n * 128 + swz(cd, n) * 8];
      acc[j] = __builtin_amdgcn_mfma_f32_16x16x32_bf16(of, bw, acc[j], 0, 0, 0);
    }
  }
  __syncthreads();                                  // Wo readers done
  // ---- prefetch W1(0)->buf0, W2(0)->buf0 (lands at FFN loop's first barrier)
#pragma unroll
  for (int u = 0; u < 2; ++u) {
    int i = w * 2 + u;
    {
      int nl = i * 4 + (l >> 4);
      int q = l & 15;
      int cc = (q & 8) | ((q & 7) ^ (nl & 7));
      GLD16(W1_d + (size_t)nl * 128 + cc * 8, &Ws[i * 512]);
    }
    {
      int n = i * 8 + (l >> 3);
      int q = l & 7;
      int kc = q ^ (n & 7);
      GLD16(W2_d + (size_t)n * 512 + kc * 8, &Ws[16384 + i * 512]);
    }
  }

  // ================ LN1, two-pass over 64-col halves (strip = [16][64])
  bf16x8 xp[4], xv[4];
  {
    float sm = 0.f, sq = 0.f;
#pragma unroll
    for (int h = 0; h < 2; ++h) {
#pragma unroll
      for (int j4 = 0; j4 < 4; ++j4) {
        int j = h * 4 + j4;
#pragma unroll
        for (int r = 0; r < 4; ++r) {
          int R = hq * 4 + r, cc = j4 * 2 + (l15 >> 3);
          st[R * 64 + (cc ^ (R & 7)) * 8 + (l15 & 7)] = f2bf(acc[j][r]);
        }
      }
      asm volatile("s_waitcnt lgkmcnt(0)" ::: "memory");
      __builtin_amdgcn_sched_barrier(0);
#pragma unroll
      for (int sp = 0; sp < 2; ++sp) {
        int s = h * 2 + sp;
        bf16x8 av = *(const bf16x8*)&st[l15 * 64 + ((sp * 4 + hq) ^ (l15 & 7)) * 8];
        xv[s] = *(const bf16x8*)&X[rbase + (size_t)l15 * 128 + s * 32 + hq * 8];
#pragma unroll
        for (int u = 0; u < 8; ++u) {
          float v = bf2f((unsigned short)av[u]) + bf2f((unsigned short)xv[s][u]);
          sm += v; sq += v * v;
        }
      }
    }
    sm += __shfl_xor(sm, 16); sm += __shfl_xor(sm, 32);
    sq += __shfl_xor(sq, 16); sq += __shfl_xor(sq, 32);
    float mu = sm * (1.f / 128.f);
    float iv = rsqrtf(sq * (1.f / 128.f) - mu * mu + 1e-5f);
    // pass 2: normalize. st currently holds half 1 -> do h=1 first, then h=0.
#pragma unroll
    for (int hh = 0; hh < 2; ++hh) {
      int h = 1 - hh;
      if (hh == 1) {     // re-transpose half 0
#pragma unroll
        for (int j4 = 0; j4 < 4; ++j4)
#pragma unroll
          for (int r = 0; r < 4; ++r) {
            int R = hq * 4 + r, cc = j4 * 2 + (l15 >> 3);
            st[R * 64 + (cc ^ (R & 7)) * 8 + (l15 & 7)] = f2bf(acc[j4][r]);
          }
        asm volatile("s_waitcnt lgkmcnt(0)" ::: "memory");
        __builtin_amdgcn_sched_barrier(0);
      }
#pragma unroll
      for (int sp = 0; sp < 2; ++sp) {
        int s = h * 2 + sp;
        bf16x8 av = *(const bf16x8*)&st[l15 * 64 + ((sp * 4 + hq) ^ (l15 & 7)) * 8];
        const float* gp = g1 + s * 32 + hq * 8;
        const float* bp = be1 + s * 32 + hq * 8;
#pragma unroll
        for (int u = 0; u < 8; ++u) {
          float v = bf2f((unsigned short)av[u]) + bf2f((unsigned short)xv[s][u]);
          xp[s][u] = (short)f2bf((v - mu) * iv * gp[u] + bp[u]);
        }
      }
    }
  }

  // ================ FFN: 8 chunks of 64 H-cols, double-buffered weights,
  // ONE barrier per chunk; staging(nc+1) overlaps compute(nc).
  f32x4 acc2[8] = {};
  int p = 0;
#pragma unroll 1
  for (int nc = 0; nc < 8; ++nc) {
    __syncthreads();                 // buf[p] ready; all waves done with buf[p^1]
    if (nc < 7) {                    // stage chunk nc+1 into buf[p^1]
#pragma unroll
      for (int u = 0; u < 2; ++u) {
        int i = w * 2 + u;
        int nl = i * 4 + (l >> 4);
        int q = l & 15;
        int cc = (q & 8) | ((q & 7) ^ (nl & 7));
        GLD16(W1_d + (size_t)((nc + 1) * 64 + nl) * 128 + cc * 8,
              &Ws[(p ^ 1) * 8192 + i * 512]);
        int n = i * 8 + (l >> 3);
        int q2 = l & 7;
        int kc = q2 ^ (n & 7);
        GLD16(W2_d + (size_t)n * 512 + (nc + 1) * 64 + kc * 8,
              &Ws[16384 + (p ^ 1) * 8192 + i * 512]);
      }
    }
    const unsigned short* W1p = Ws + p * 8192;
    const unsigned short* W2p = Ws + 16384 + p * 8192;
    // FFN1 chunk: a1[4] -> 4 independent MFMA chains
    f32x4 a1[4] = {};
#pragma unroll
    for (int s = 0; s < 4; ++s) {
      int cd = s * 4 + hq;
#pragma unroll
      for (int jj = 0; jj < 4; ++jj) {
        int nl = jj * 16 + l15;
        bf16x8 bw = *(const bf16x8*)&W1p[nl * 128 + swz(cd, nl) * 8];
        a1[jj] = __builtin_amdgcn_mfma_f32_16x16x32_bf16(xp[s], bw, a1[jj], 0, 0, 0);
      }
    }
#pragma unroll
    for (int jj = 0; jj < 4; ++jj) {
      float bv = b1d[nc * 64 + jj * 16 + l15];
#pragma unroll
      for (int r = 0; r < 4; ++r) {
        int R = hq * 4 + r, cc = jj * 2 + (l15 >> 3);
        st[R * 64 + (cc ^ (R & 7)) * 8 + (l15 & 7)] = f2bf(fmaxf(a1[jj][r] + bv, 0.f));
      }
    }
    asm volatile("s_waitcnt lgkmcnt(0)" ::: "memory");
    __builtin_amdgcn_sched_barrier(0);
    bf16x8 hf[2];
#pragma unroll
    for (int sl = 0; sl < 2; ++sl)
      hf[sl] = *(const bf16x8*)&st[l15 * 64 + ((sl * 4 + hq) ^ (l15 & 7)) * 8];
    // FFN2 chunk from W2 buffer
#pragma unroll
    for (int sl = 0; sl < 2; ++sl) {
      int kc = sl * 4 + hq;
#pragma unroll
      for (int j = 0; j < 8; ++j) {
        int n = j * 16 + l15;
        bf16x8 bw = *(const bf16x8*)&W2p[n * 64 + (kc ^ (n & 7)) * 8];
        acc2[j] = __builtin_amdgcn_mfma_f32_16x16x32_bf16(hf[sl], bw, acc2[j], 0, 0, 0);
      }
    }
    p ^= 1;
  }

  // ================ + b2, two-pass LN2 (residual = xp), store X
  {
    float sm = 0.f, sq = 0.f;
#pragma unroll
    for (int h = 0; h < 2; ++h) {
#pragma unroll
      for (int j4 = 0; j4 < 4; ++j4) {
        int j = h * 4 + j4;
        float bv = b2d[j * 16 + l15];
#pragma unroll
        for (int r = 0; r < 4; ++r) {
          int R = hq * 4 + r, cc = j4 * 2 + (l15 >> 3);
          st[R * 64 + (cc ^ (R & 7)) * 8 + (l15 & 7)] = f2bf(acc2[j][r] + bv);
        }
      }
      asm volatile("s_waitcnt lgkmcnt(0)" ::: "memory");
      __builtin_amdgcn_sched_barrier(0);
#pragma unroll
      for (int sp = 0; sp < 2; ++sp) {
        int s = h * 2 + sp;
        bf16x8 av = *(const bf16x8*)&st[l15 * 64 + ((sp * 4 + hq) ^ (l15 & 7)) * 8];
#pragma unroll
        for (int u = 0; u < 8; ++u) {
          float v = bf2f((unsigned short)av[u]) + bf2f((unsigned short)xp[s][u]);
          sm += v; sq += v * v;
        }
      }
    }
    sm += __shfl_xor(sm, 16); sm += __shfl_xor(sm, 32);
    sq += __shfl_xor(sq, 16); sq += __shfl_xor(sq, 32);
    float mu = sm * (1.f / 128.f);
    float iv = rsqrtf(sq * (1.f / 128.f) - mu * mu + 1e-5f);
#pragma unroll
    for (int hh = 0; hh < 2; ++hh) {
      int h = 1 - hh;
      if (hh == 1) {     // re-transpose half 0 (+bias)
#pragma unroll
        for (int j4 = 0; j4 < 4; ++j4) {
          float bv = b2d[j4 * 16 + l15];
#pragma unroll
          for (int r = 0; r < 4; ++r) {
            int R = hq * 4 + r, cc = j4 * 2 + (l15 >> 3);
            st[R * 64 + (cc ^ (R & 7)) * 8 + (l15 & 7)] = f2bf(acc2[j4][r] + bv);
          }
        }
        asm volatile("s_waitcnt lgkmcnt(0)" ::: "memory");
        __builtin_amdgcn_sched_barrier(0);
      }
#pragma unroll
      for (int sp = 0; sp < 2; ++sp) {
        int s = h * 2 + sp;
        bf16x8 av = *(const bf16x8*)&st[l15 * 64 + ((sp * 4 + hq) ^ (l15 & 7)) * 8];
        const float* gp = g2 + s * 32 + hq * 8;
        const float* bp = be2 + s * 32 + hq * 8;
        bf16x8 ov;
#pragma unroll
        for (int u2 = 0; u2 < 4; ++u2) {
          float v0 = bf2f((unsigned short)av[u2 * 2]) + bf2f((unsigned short)xp[s][u2 * 2]);
          float v1 = bf2f((unsigned short)av[u2 * 2 + 1]) + bf2f((unsigned short)xp[s][u2 * 2 + 1]);
          float o0 = (v0 - mu) * iv * gp[u2 * 2] + bp[u2 * 2];
          float o1 = (v1 - mu) * iv * gp[u2 * 2 + 1] + bp[u2 * 2 + 1];
          ((unsigned*)&ov)[u2] = packbf(o0, o1);
        }
        *(bf16x8*)&X[rbase + (size_t)l15 * 128 + s * 32 + hq * 8] = ov;
      }
    }
  }
}

// ---------------------------------------------------------------- decoders
__global__ __launch_bounds__(64) void decode_kernel(
    const unsigned short* __restrict__ X, const float* __restrict__ Wdn,
    const float* __restrict__ bdn, const float* __restrict__ Wdc,
    const float* __restrict__ bdc, const int* __restrict__ pin,
    const int* __restrict__ pic, const int* __restrict__ cards,
    float* __restrict__ out)
{
  __shared__ float tokc[128];
  int b = blockIdx.x, t = threadIdx.x;
  int idn = pin[b];
  const unsigned short* xr = X + (size_t)(b * cF + idn) * cE;
  float p = bf2f(xr[t]) * Wdn[idn * cE + t] + bf2f(xr[t + 64]) * Wdn[idn * cE + t + 64];
#pragma unroll
  for (int off = 32; off; off >>= 1) p += __shfl_xor(p, off);
  if (t == 0) out[b] = p + bdn[idn];
  int idc = pic[b];
  const unsigned short* xc = X + (size_t)(b * cF + idc) * cE;
  tokc[t] = bf2f(xc[t]);
  tokc[t + 64] = bf2f(xc[t + 64]);
  __syncthreads();
  float acc = bdc[idc * cMC + t];
  const float* wv = Wdc + (size_t)idc * cE * cMC + t;
  for (int e2 = 0; e2 < 128; ++e2) acc += tokc[e2] * wv[(size_t)e2 * cMC];
  int card = cards[idc];
  out[cB + b * cMC + t] = (t >= card) ? -100.f : acc;
}

// ---------------------------------------------------------------- launch
extern "C" void kernel_launch(void* const* d_in, const int* in_sizes, int n_in,
                              void* d_out, int out_size, void* d_ws, size_t ws_size,
                              hipStream_t stream)
{
  const float* x_num    = (const float*)d_in[0];
  const float* W_numtok = (const float*)d_in[1];
  const float* b_numtok = (const float*)d_in[2];
  const float* E_cat    = (const float*)d_in[3];
  const float* b_cattok = (const float*)d_in[4];
  const float* mask_tok = (const float*)d_in[5];
  const float* random_prob = (const float*)d_in[6];
  const float* rand_num = (const float*)d_in[7];
  const float* rand_cat = (const float*)d_in[8];
  const float* Wq   = (const float*)d_in[9];
  const float* Wk   = (const float*)d_in[10];
  const float* Wv   = (const float*)d_in[11];
  const float* Wo   = (const float*)d_in[12];
  const float* ln1g = (const float*)d_in[13];
  const float* ln1b = (const float*)d_in[14];
  const float* W1   = (const float*)d_in[15];
  const float* b1   = (const float*)d_in[16];
  const float* W2   = (const float*)d_in[17];
  const float* b2   = (const float*)d_in[18];
  const float* ln2g = (const float*)d_in[19];
  const float* ln2b = (const float*)d_in[20];
  const float* Wdn  = (const float*)d_in[21];
  const float* bdn  = (const float*)d_in[22];
  const float* Wdc  = (const float*)d_in[23];
  const float* bdc  = (const float*)d_in[24];
  const int* x_cat    = (const int*)d_in[25];
  const int* mask_num = (const int*)d_in[26];
  const int* mask_cat = (const int*)d_in[27];
  const int* pin      = (const int*)d_in[28];
  const int* pic      = (const int*)d_in[29];
  const int* cards    = (const int*)d_in[30];
  float* out = (float*)d_out;

  unsigned short* Wqkv_t = (unsigned short*)d_ws;           // 4*384*128
  unsigned short* Wo_t   = Wqkv_t + (size_t)4 * 384 * 128;  // 4*128*128
  unsigned short* W1_t   = Wo_t + (size_t)4 * 128 * 128;    // 4*512*128
  unsigned short* W2_t   = W1_t + (size_t)4 * 512 * 128;    // 4*128*512
  float* pe = (float*)(W2_t + (size_t)4 * 128 * 512);       // 16384 f32
  unsigned short* Xact = (unsigned short*)(pe + 16384);     // TOK*128
  unsigned short* Oact = Xact + (size_t)TOK * 128;          // TOK*128

  setup_kernel<<<3136, 256, 0, stream>>>(Wq, Wk, Wv, Wo, W1, W2,
      Wqkv_t, Wo_t, W1_t, W2_t, pe);

  embed_kernel<<<TOK / 2, 256, 0, stream>>>(x_num, W_numtok, b_numtok, E_cat,
      b_cattok, mask_tok, random_prob, rand_num, rand_cat, x_cat, mask_num,
      mask_cat, pe, Xact);

  for (int d = 0; d < cD; ++d) {
    qkv_attn_kernel<<<cB * 4, 512, 0, stream>>>(
        Xact, Wqkv_t + (size_t)d * 384 * 128, Oact);
    ffn_kernel<<<TOK / 128, 512, 0, stream>>>(
        Oact, Xact, Wo_t + (size_t)d * 128 * 128,
        W1_t + (size_t)d * 512 * 128, W2_t + (size_t)d * 128 * 512,
        ln1g + d * cE, ln1b + d * cE, ln2g + d * cE, ln2b + d * cE,
        b1 + d * cFF, b2 + d * cE);
  }

  decode_kernel<<<cB, 64, 0, stream>>>(Xact, Wdn, bdn, Wdc, bdc, pin, pic, cards, out);
}

// Round 19
// 348.008 us; speedup vs baseline: 1.0821x; 1.0681x over previous
//
#include <hip/hip_runtime.h>
#include <hip/hip_bf16.h>

typedef __attribute__((ext_vector_type(8))) short bf16x8;
typedef __attribute__((ext_vector_type(4))) float f32x4;

constexpr int cB = 512, cNN = 96, cNC = 32, cF = 128, cE = 128,
              cH = 8, cDH = 16, cFF = 512, cD = 4, cMC = 64;
constexpr int TOK = cB * cF;

__device__ __forceinline__ float bf2f(unsigned short u) {
  union { float f; unsigned i; } v; v.i = ((unsigned)u) << 16; return v.f;
}
__device__ __forceinline__ unsigned short f2bf(float f) {
  __hip_bfloat16 h = __float2bfloat16(f);
  return *reinterpret_cast<unsigned short*>(&h);
}
__device__ __forceinline__ unsigned packbf(float a, float b) {
  __hip_bfloat162 h = __float22bfloat162_rn(make_float2(a, b));
  return *reinterpret_cast<unsigned*>(&h);
}
// XOR-swizzle of 16B-chunk index within aligned 8-chunk groups (involution)
__device__ __forceinline__ int swz(int c, int r) {
  return (c & ~7) | ((c & 7) ^ (r & 7));
}

#define GLD16(g, l) __builtin_amdgcn_global_load_lds( \
    (const __attribute__((address_space(1))) void*)(g), \
    (__attribute__((address_space(3))) void*)(l), 16, 0, 0)

// ---------------------------------------------------------------- setup
// one launch: pe table + all 6 weight packs, range-dispatched on blockIdx.
__global__ __launch_bounds__(256) void setup_kernel(
    const float* __restrict__ Wq, const float* __restrict__ Wk,
    const float* __restrict__ Wv, const float* __restrict__ Wo,
    const float* __restrict__ W1, const float* __restrict__ W2,
    unsigned short* __restrict__ Wqkv_t, unsigned short* __restrict__ Wo_t,
    unsigned short* __restrict__ W1_t, unsigned short* __restrict__ W2_t,
    float* __restrict__ pe)
{
  int bid = blockIdx.x;
  if (bid < 64) {
    int idx = bid * 256 + threadIdx.x;              // 128*128
    int f = idx >> 7, e = idx & 127;
    int i = e >> 1;
    float ang = (float)f * expf(-(float)(2 * i) * 0.07195578415606394f);
    pe[idx] = (e & 1) ? cosf(ang) : sinf(ang);
    return;
  }
  const float* src; unsigned short* dst;
  int K, N, nStride, nOff, base;
  if (bid < 320)       { src = Wq; dst = Wqkv_t; K = 128; N = 128; nStride = 384; nOff = 0;   base = 64; }
  else if (bid < 576)  { src = Wk; dst = Wqkv_t; K = 128; N = 128; nStride = 384; nOff = 128; base = 320; }
  else if (bid < 832)  { src = Wv; dst = Wqkv_t; K = 128; N = 128; nStride = 384; nOff = 256; base = 576; }
  else if (bid < 1088) { src = Wo; dst = Wo_t;   K = 128; N = 128; nStride = 128; nOff = 0;   base = 832; }
  else if (bid < 2112) { src = W1; dst = W1_t;   K = 128; N = 512; nStride = 512; nOff = 0;   base = 1088; }
  else                 { src = W2; dst = W2_t;   K = 512; N = 128; nStride = 128; nOff = 0;   base = 2112; }
  int idx = (bid - base) * 256 + threadIdx.x;
  int k = idx % K;
  int rem = idx / K;
  int n = rem % N;
  int d = rem / N;
  dst[((size_t)d * nStride + nOff + n) * K + k] =
      f2bf(src[((size_t)d * K + k) * N + n]);
}

// ---------------------------------------------------------------- embed
__global__ __launch_bounds__(256) void embed_kernel(
    const float* __restrict__ x_num, const float* __restrict__ W_numtok,
    const float* __restrict__ b_numtok, const float* __restrict__ E_cat,
    const float* __restrict__ b_cattok, const float* __restrict__ mask_tok,
    const float* __restrict__ random_prob, const float* __restrict__ rand_num,
    const float* __restrict__ rand_cat, const int* __restrict__ x_cat,
    const int* __restrict__ mask_num, const int* __restrict__ mask_cat,
    const float* __restrict__ pe, unsigned short* __restrict__ X)
{
  int token = blockIdx.x * 2 + (threadIdx.x >> 7);
  int e = threadIdx.x & 127;
  int b = token >> 7, f = token & 127;
  float v;
  if (f < cNN) {
    v = x_num[b * cNN + f] * W_numtok[f * cE + e] + b_numtok[f * cE + e];
  } else {
    int c = f - cNN;
    int idx = x_cat[b * cNC + c];
    v = E_cat[(c * cMC + idx) * cE + e] + b_cattok[c * cE + e];
  }
  float rp = random_prob[b];
  bool mn = mask_num[b * cF + f] != 0;
  bool mc = mask_cat[b * cF + f] != 0;
  if (rp < 0.8f) {
    if (!mn || !mc) v = mask_tok[e];
  } else if (rp < 0.9f) {
    if (!mn) v = rand_num[(b * cF + f) * cE + e];
    if (!mc) v = rand_cat[(b * cF + f) * cE + e];
  }
  v += pe[f * cE + e];
  X[(size_t)token * cE + e] = f2bf(v);
}

// ---------------------------------------------------------------- kernel A
// grid = (b, head-pair). QKV weights + per-wave X rows staged into LDS via
// coalesced global_load_lds; all MFMA operands from LDS. (r16 exact)
__global__ __launch_bounds__(512, 2) void qkv_attn_kernel(
    const unsigned short* __restrict__ X, const unsigned short* __restrict__ Wt,
    unsigned short* __restrict__ O)
{
  __shared__ unsigned short Qs[128 * 32];    // 8KB, chunk c^(row&3)
  __shared__ unsigned short Ks[128 * 32];    // 8KB
  __shared__ unsigned short Vt[2 * 16 * 128];// 8KB, [lh][dh][g] swz(g>>3,dh)
  __shared__ unsigned short Ws[96 * 128];    // 24KB staged QKV weights
  __shared__ unsigned short PX[8 * 2048];    // 32KB: per-wave X rows, then P strips
  const int tid = threadIdx.x;
  const int b = blockIdx.x >> 2, hp = blockIdx.x & 3;
  const int w = tid >> 6, l = tid & 63, hq = l >> 4, l15 = l & 15;
  const unsigned short* Xg = X + (size_t)b * 128 * 128;

  // ---- stage: per-wave X rows (16x128 swizzled) + block-wide weight slice
#pragma unroll
  for (int r = 0; r < 4; ++r) {
    int row16 = r * 4 + (l >> 4);
    int cl = l & 15;
    int sc = (cl & 8) | ((cl & 7) ^ (row16 & 7));
    GLD16(Xg + (w * 16 + row16) * 128 + sc * 8, &PX[w * 2048 + r * 512]);
  }
#pragma unroll
  for (int u = 0; u < 3; ++u) {
    int lr = u * 32 + (tid >> 4);
    int cl = tid & 15;
    int sc = (cl & 8) | ((cl & 7) ^ (lr & 7));
    int ng = (lr >> 5) * 128 + hp * 32 + (lr & 31);
    GLD16(Wt + ng * 128 + sc * 8, &Ws[u * 4096 + (w * 64) * 8]);
  }
  __syncthreads();

  // ---- QKV: wave w owns rows w*16..+15; 6 col-tiles (Q0 Q1 K0 K1 V0 V1)
  {
    f32x4 acc[6] = {};
#pragma unroll
    for (int s = 0; s < 4; ++s) {
      int cd = s * 4 + hq;
      int cr = (cd & 8) | ((cd & 7) ^ (l15 & 7));
      bf16x8 af = *(const bf16x8*)&PX[w * 2048 + l15 * 128 + cr * 8];
#pragma unroll
      for (int j = 0; j < 6; ++j) {
        int ln = (j >> 1) * 32 + (j & 1) * 16 + l15;
        int cr2 = (cd & 8) | ((cd & 7) ^ (ln & 7));
        bf16x8 bw = *(const bf16x8*)&Ws[ln * 128 + cr2 * 8];
        acc[j] = __builtin_amdgcn_mfma_f32_16x16x32_bf16(af, bw, acc[j], 0, 0, 0);
      }
    }
    const int r0 = w * 16 + hq * 4;
#pragma unroll
    for (int j = 0; j < 6; ++j) {
      if (j < 4) {
        unsigned short* dst = (j < 2) ? Qs : Ks;
        int col = (j & 1) * 16 + l15;
#pragma unroll
        for (int r = 0; r < 4; ++r) {
          int row2 = r0 + r;
          dst[row2 * 32 + ((col >> 3) ^ (row2 & 3)) * 8 + (col & 7)] = f2bf(acc[j][r]);
        }
      } else {
        int lh = j - 4, dh = l15;
#pragma unroll
        for (int rp = 0; rp < 2; ++rp) {
          int g = r0 + rp * 2;
          unsigned pk = packbf(acc[j][rp * 2], acc[j][rp * 2 + 1]);
          *(unsigned*)&Vt[lh * 2048 + dh * 128 + ((g >> 3) ^ (dh & 7)) * 8 + (g & 7)] = pk;
        }
      }
    }
  }
  __syncthreads();

  // ---- attention: 4 waves per head (lh = w>>2), each wave 2 row-groups of 16
  {
    const int lh = w >> 2, wq = w & 3, h = hp * 2 + lh;
    const bf16x8 zfrag = {0, 0, 0, 0, 0, 0, 0, 0};
#pragma unroll 1
    for (int ft2 = 0; ft2 < 2; ++ft2) {
      int ft = wq * 2 + ft2;
      int f = ft * 16 + l15;
      bf16x8 bq = zfrag;
      if (hq < 2) bq = *(const bf16x8*)&Qs[f * 32 + ((lh * 2 + hq) ^ (f & 3)) * 8];
      f32x4 sa[8];
#pragma unroll
      for (int gt = 0; gt < 8; ++gt) {
        int g = gt * 16 + l15;
        bf16x8 ak = zfrag;
        if (hq < 2) ak = *(const bf16x8*)&Ks[g * 32 + ((lh * 2 + hq) ^ (g & 3)) * 8];
        f32x4 z = {0.f, 0.f, 0.f, 0.f};
        sa[gt] = __builtin_amdgcn_mfma_f32_16x16x32_bf16(ak, bq, z, 0, 0, 0);
      }
      float mx = -3.0e38f;
#pragma unroll
      for (int gt = 0; gt < 8; ++gt)
#pragma unroll
        for (int r = 0; r < 4; ++r) mx = fmaxf(mx, sa[gt][r]);
      mx = fmaxf(mx, __shfl_xor(mx, 16));
      mx = fmaxf(mx, __shfl_xor(mx, 32));
      float mm = mx * 0.25f;
      float sum = 0.f;
#pragma unroll
      for (int gt = 0; gt < 8; ++gt)
#pragma unroll
        for (int r = 0; r < 4; ++r) {
          float e = __expf(fmaf(sa[gt][r], 0.25f, -mm));
          sa[gt][r] = e;
          sum += e;
        }
      sum += __shfl_xor(sum, 16);
      sum += __shfl_xor(sum, 32);
      float inv = 1.f / sum;
      f32x4 oa = {0.f, 0.f, 0.f, 0.f};
#pragma unroll
      for (int gh = 0; gh < 2; ++gh) {
#pragma unroll
        for (int g2 = 0; g2 < 4; ++g2) {
          int gt = gh * 4 + g2;
#pragma unroll
          for (int rp = 0; rp < 2; ++rp) {
            unsigned pk = packbf(sa[gt][rp * 2], sa[gt][rp * 2 + 1]);
            int gl = g2 * 16 + hq * 4 + rp * 2;
            *(unsigned*)&PX[w * 2048 + l15 * 64 + ((gl >> 3) ^ (l15 & 7)) * 8 + (gl & 7)] = pk;
          }
        }
        asm volatile("s_waitcnt lgkmcnt(0)" ::: "memory");
        __builtin_amdgcn_sched_barrier(0);
#pragma unroll
        for (int s2 = 0; s2 < 2; ++s2) {
          bf16x8 pa = *(const bf16x8*)&PX[w * 2048 + l15 * 64 + ((s2 * 4 + hq) ^ (l15 & 7)) * 8];
          int cgv = gh * 8 + s2 * 4 + hq;
          bf16x8 bv = *(const bf16x8*)&Vt[lh * 2048 + l15 * 128 + swz(cgv, l15) * 8];
          oa = __builtin_amdgcn_mfma_f32_16x16x32_bf16(pa, bv, oa, 0, 0, 0);
        }
      }
#pragma unroll
      for (int r = 0; r < 4; ++r) {
        int fo = ft * 16 + hq * 4 + r;
        O[((size_t)b * 128 + fo) * 128 + h * 16 + l15] =
            f2bf(oa[r] * __shfl(inv, hq * 4 + r));
      }
    }
  }
}

// ---------------------------------------------------------------- kernel B
// r16 exact: double-buffered weight LDS, register-resident rows, a1[4].
__global__ __launch_bounds__(512, 2) void ffn_kernel(
    const unsigned short* __restrict__ O, unsigned short* __restrict__ X,
    const unsigned short* __restrict__ Wo_d, const unsigned short* __restrict__ W1_d,
    const unsigned short* __restrict__ W2_d,
    const float* __restrict__ g1, const float* __restrict__ be1,
    const float* __restrict__ g2, const float* __restrict__ be2,
    const float* __restrict__ b1d, const float* __restrict__ b2d)
{
  __shared__ unsigned short strip[8][1024];   // 2KB per wave (16KB)
  __shared__ unsigned short Ws[32768];        // 64KB: W1buf0|W1buf1|W2buf0|W2buf1
  const int w = threadIdx.x >> 6, l = threadIdx.x & 63;
  const int hq = l >> 4, l15 = l & 15;
  const size_t rbase = ((size_t)blockIdx.x * 8 + w) * 16 * 128;  // wave's 16 rows
  unsigned short* st = strip[w];

  // ---- stage Wo (128x128 = 32KB) into Ws[0..16383]
#pragma unroll
  for (int u = 0; u < 4; ++u) {
    int i = w * 4 + u;
    int n = i * 4 + (l >> 4);
    int q = l & 15;
    int cc = (q & 8) | ((q & 7) ^ (n & 7));
    GLD16(Wo_d + n * 128 + cc * 8, &Ws[i * 512]);
  }
  __syncthreads();                                  // Ws(Wo) ready

  // ================ Wo: A = O row-frags (global, own rows), B from Ws
  f32x4 acc[8] = {};
#pragma unroll
  for (int s = 0; s < 4; ++s) {
    bf16x8 of = *(const bf16x8*)&O[rbase + (size_t)l15 * 128 + s * 32 + hq * 8];
    int cd = s * 4 + hq;
#pragma unroll
    for (int j = 0; j < 8; ++j) {
      int n = j * 16 + l15;
      bf16x8 bw = *(const bf16x8*)&Ws[n * 128 + swz(cd, n) * 8];
      acc[j] = __builtin_amdgcn_mfma_f32_16x16x32_bf16(of, bw, acc[j], 0, 0, 0);
    }
  }
  __syncthreads();                                  // Wo readers done
  // ---- prefetch W1(0)->buf0, W2(0)->buf0 (lands at FFN loop's first barrier)
#pragma unroll
  for (int u = 0; u < 2; ++u) {
    int i = w * 2 + u;
    {
      int nl = i * 4 + (l >> 4);
      int q = l & 15;
      int cc = (q & 8) | ((q & 7) ^ (nl & 7));
      GLD16(W1_d + (size_t)nl * 128 + cc * 8, &Ws[i * 512]);
    }
    {
      int n = i * 8 + (l >> 3);
      int q = l & 7;
      int kc = q ^ (n & 7);
      GLD16(W2_d + (size_t)n * 512 + kc * 8, &Ws[16384 + i * 512]);
    }
  }

  // ================ LN1, two-pass over 64-col halves (strip = [16][64])
  bf16x8 xp[4], xv[4];
  {
    float sm = 0.f, sq = 0.f;
#pragma unroll
    for (int h = 0; h < 2; ++h) {
#pragma unroll
      for (int j4 = 0; j4 < 4; ++j4) {
        int j = h * 4 + j4;
#pragma unroll
        for (int r = 0; r < 4; ++r) {
          int R = hq * 4 + r, cc = j4 * 2 + (l15 >> 3);
          st[R * 64 + (cc ^ (R & 7)) * 8 + (l15 & 7)] = f2bf(acc[j][r]);
        }
      }
      asm volatile("s_waitcnt lgkmcnt(0)" ::: "memory");
      __builtin_amdgcn_sched_barrier(0);
#pragma unroll
      for (int sp = 0; sp < 2; ++sp) {
        int s = h * 2 + sp;
        bf16x8 av = *(const bf16x8*)&st[l15 * 64 + ((sp * 4 + hq) ^ (l15 & 7)) * 8];
        xv[s] = *(const bf16x8*)&X[rbase + (size_t)l15 * 128 + s * 32 + hq * 8];
#pragma unroll
        for (int u = 0; u < 8; ++u) {
          float v = bf2f((unsigned short)av[u]) + bf2f((unsigned short)xv[s][u]);
          sm += v; sq += v * v;
        }
      }
    }
    sm += __shfl_xor(sm, 16); sm += __shfl_xor(sm, 32);
    sq += __shfl_xor(sq, 16); sq += __shfl_xor(sq, 32);
    float mu = sm * (1.f / 128.f);
    float iv = rsqrtf(sq * (1.f / 128.f) - mu * mu + 1e-5f);
    // pass 2: normalize. st currently holds half 1 -> do h=1 first, then h=0.
#pragma unroll
    for (int hh = 0; hh < 2; ++hh) {
      int h = 1 - hh;
      if (hh == 1) {     // re-transpose half 0
#pragma unroll
        for (int j4 = 0; j4 < 4; ++j4)
#pragma unroll
          for (int r = 0; r < 4; ++r) {
            int R = hq * 4 + r, cc = j4 * 2 + (l15 >> 3);
            st[R * 64 + (cc ^ (R & 7)) * 8 + (l15 & 7)] = f2bf(acc[j4][r]);
          }
        asm volatile("s_waitcnt lgkmcnt(0)" ::: "memory");
        __builtin_amdgcn_sched_barrier(0);
      }
#pragma unroll
      for (int sp = 0; sp < 2; ++sp) {
        int s = h * 2 + sp;
        bf16x8 av = *(const bf16x8*)&st[l15 * 64 + ((sp * 4 + hq) ^ (l15 & 7)) * 8];
        const float* gp = g1 + s * 32 + hq * 8;
        const float* bp = be1 + s * 32 + hq * 8;
#pragma unroll
        for (int u = 0; u < 8; ++u) {
          float v = bf2f((unsigned short)av[u]) + bf2f((unsigned short)xv[s][u]);
          xp[s][u] = (short)f2bf((v - mu) * iv * gp[u] + bp[u]);
        }
      }
    }
  }

  // ================ FFN: 8 chunks of 64 H-cols, double-buffered weights,
  // ONE barrier per chunk; staging(nc+1) overlaps compute(nc).
  f32x4 acc2[8] = {};
  int p = 0;
#pragma unroll 1
  for (int nc = 0; nc < 8; ++nc) {
    __syncthreads();                 // buf[p] ready; all waves done with buf[p^1]
    if (nc < 7) {                    // stage chunk nc+1 into buf[p^1]
#pragma unroll
      for (int u = 0; u < 2; ++u) {
        int i = w * 2 + u;
        int nl = i * 4 + (l >> 4);
        int q = l & 15;
        int cc = (q & 8) | ((q & 7) ^ (nl & 7));
        GLD16(W1_d + (size_t)((nc + 1) * 64 + nl) * 128 + cc * 8,
              &Ws[(p ^ 1) * 8192 + i * 512]);
        int n = i * 8 + (l >> 3);
        int q2 = l & 7;
        int kc = q2 ^ (n & 7);
        GLD16(W2_d + (size_t)n * 512 + (nc + 1) * 64 + kc * 8,
              &Ws[16384 + (p ^ 1) * 8192 + i * 512]);
      }
    }
    const unsigned short* W1p = Ws + p * 8192;
    const unsigned short* W2p = Ws + 16384 + p * 8192;
    // FFN1 chunk: a1[4] -> 4 independent MFMA chains
    f32x4 a1[4] = {};
#pragma unroll
    for (int s = 0; s < 4; ++s) {
      int cd = s * 4 + hq;
#pragma unroll
      for (int jj = 0; jj < 4; ++jj) {
        int nl = jj * 16 + l15;
        bf16x8 bw = *(const bf16x8*)&W1p[nl * 128 + swz(cd, nl) * 8];
        a1[jj] = __builtin_amdgcn_mfma_f32_16x16x32_bf16(xp[s], bw, a1[jj], 0, 0, 0);
      }
    }
#pragma unroll
    for (int jj = 0; jj < 4; ++jj) {
      float bv = b1d[nc * 64 + jj * 16 + l15];
#pragma unroll
      for (int r = 0; r < 4; ++r) {
        int R = hq * 4 + r, cc = jj * 2 + (l15 >> 3);
        st[R * 64 + (cc ^ (R & 7)) * 8 + (l15 & 7)] = f2bf(fmaxf(a1[jj][r] + bv, 0.f));
      }
    }
    asm volatile("s_waitcnt lgkmcnt(0)" ::: "memory");
    __builtin_amdgcn_sched_barrier(0);
    bf16x8 hf[2];
#pragma unroll
    for (int sl = 0; sl < 2; ++sl)
      hf[sl] = *(const bf16x8*)&st[l15 * 64 + ((sl * 4 + hq) ^ (l15 & 7)) * 8];
    // FFN2 chunk from W2 buffer
#pragma unroll
    for (int sl = 0; sl < 2; ++sl) {
      int kc = sl * 4 + hq;
#pragma unroll
      for (int j = 0; j < 8; ++j) {
        int n = j * 16 + l15;
        bf16x8 bw = *(const bf16x8*)&W2p[n * 64 + (kc ^ (n & 7)) * 8];
        acc2[j] = __builtin_amdgcn_mfma_f32_16x16x32_bf16(hf[sl], bw, acc2[j], 0, 0, 0);
      }
    }
    p ^= 1;
  }

  // ================ + b2, two-pass LN2 (residual = xp), store X
  {
    float sm = 0.f, sq = 0.f;
#pragma unroll
    for (int h = 0; h < 2; ++h) {
#pragma unroll
      for (int j4 = 0; j4 < 4; ++j4) {
        int j = h * 4 + j4;
        float bv = b2d[j * 16 + l15];
#pragma unroll
        for (int r = 0; r < 4; ++r) {
          int R = hq * 4 + r, cc = j4 * 2 + (l15 >> 3);
          st[R * 64 + (cc ^ (R & 7)) * 8 + (l15 & 7)] = f2bf(acc2[j][r] + bv);
        }
      }
      asm volatile("s_waitcnt lgkmcnt(0)" ::: "memory");
      __builtin_amdgcn_sched_barrier(0);
#pragma unroll
      for (int sp = 0; sp < 2; ++sp) {
        int s = h * 2 + sp;
        bf16x8 av = *(const bf16x8*)&st[l15 * 64 + ((sp * 4 + hq) ^ (l15 & 7)) * 8];
#pragma unroll
        for (int u = 0; u < 8; ++u) {
          float v = bf2f((unsigned short)av[u]) + bf2f((unsigned short)xp[s][u]);
          sm += v; sq += v * v;
        }
      }
    }
    sm += __shfl_xor(sm, 16); sm += __shfl_xor(sm, 32);
    sq += __shfl_xor(sq, 16); sq += __shfl_xor(sq, 32);
    float mu = sm * (1.f / 128.f);
    float iv = rsqrtf(sq * (1.f / 128.f) - mu * mu + 1e-5f);
#pragma unroll
    for (int hh = 0; hh < 2; ++hh) {
      int h = 1 - hh;
      if (hh == 1) {     // re-transpose half 0 (+bias)
#pragma unroll
        for (int j4 = 0; j4 < 4; ++j4) {
          float bv = b2d[j4 * 16 + l15];
#pragma unroll
          for (int r = 0; r < 4; ++r) {
            int R = hq * 4 + r, cc = j4 * 2 + (l15 >> 3);
            st[R * 64 + (cc ^ (R & 7)) * 8 + (l15 & 7)] = f2bf(acc2[j4][r] + bv);
          }
        }
        asm volatile("s_waitcnt lgkmcnt(0)" ::: "memory");
        __builtin_amdgcn_sched_barrier(0);
      }
#pragma unroll
      for (int sp = 0; sp < 2; ++sp) {
        int s = h * 2 + sp;
        bf16x8 av = *(const bf16x8*)&st[l15 * 64 + ((sp * 4 + hq) ^ (l15 & 7)) * 8];
        const float* gp = g2 + s * 32 + hq * 8;
        const float* bp = be2 + s * 32 + hq * 8;
        bf16x8 ov;
#pragma unroll
        for (int u2 = 0; u2 < 4; ++u2) {
          float v0 = bf2f((unsigned short)av[u2 * 2]) + bf2f((unsigned short)xp[s][u2 * 2]);
          float v1 = bf2f((unsigned short)av[u2 * 2 + 1]) + bf2f((unsigned short)xp[s][u2 * 2 + 1]);
          float o0 = (v0 - mu) * iv * gp[u2 * 2] + bp[u2 * 2];
          float o1 = (v1 - mu) * iv * gp[u2 * 2 + 1] + bp[u2 * 2 + 1];
          ((unsigned*)&ov)[u2] = packbf(o0, o1);
        }
        *(bf16x8*)&X[rbase + (size_t)l15 * 128 + s * 32 + hq * 8] = ov;
      }
    }
  }
}

// ---------------------------------------------------------------- decoders
__global__ __launch_bounds__(64) void decode_kernel(
    const unsigned short* __restrict__ X, const float* __restrict__ Wdn,
    const float* __restrict__ bdn, const float* __restrict__ Wdc,
    const float* __restrict__ bdc, const int* __restrict__ pin,
    const int* __restrict__ pic, const int* __restrict__ cards,
    float* __restrict__ out)
{
  __shared__ float tokc[128];
  int b = blockIdx.x, t = threadIdx.x;
  int idn = pin[b];
  const unsigned short* xr = X + (size_t)(b * cF + idn) * cE;
  float p = bf2f(xr[t]) * Wdn[idn * cE + t] + bf2f(xr[t + 64]) * Wdn[idn * cE + t + 64];
#pragma unroll
  for (int off = 32; off; off >>= 1) p += __shfl_xor(p, off);
  if (t == 0) out[b] = p + bdn[idn];
  int idc = pic[b];
  const unsigned short* xc = X + (size_t)(b * cF + idc) * cE;
  tokc[t] = bf2f(xc[t]);
  tokc[t + 64] = bf2f(xc[t + 64]);
  __syncthreads();
  float acc = bdc[idc * cMC + t];
  const float* wv = Wdc + (size_t)idc * cE * cMC + t;
  for (int e2 = 0; e2 < 128; ++e2) acc += tokc[e2] * wv[(size_t)e2 * cMC];
  int card = cards[idc];
  out[cB + b * cMC + t] = (t >= card) ? -100.f : acc;
}

// ---------------------------------------------------------------- launch
extern "C" void kernel_launch(void* const* d_in, const int* in_sizes, int n_in,
                              void* d_out, int out_size, void* d_ws, size_t ws_size,
                              hipStream_t stream)
{
  const float* x_num    = (const float*)d_in[0];
  const float* W_numtok = (const float*)d_in[1];
  const float* b_numtok = (const float*)d_in[2];
  const float* E_cat    = (const float*)d_in[3];
  const float* b_cattok = (const float*)d_in[4];
  const float* mask_tok = (const float*)d_in[5];
  const float* random_prob = (const float*)d_in[6];
  const float* rand_num = (const float*)d_in[7];
  const float* rand_cat = (const float*)d_in[8];
  const float* Wq   = (const float*)d_in[9];
  const float* Wk   = (const float*)d_in[10];
  const float* Wv   = (const float*)d_in[11];
  const float* Wo   = (const float*)d_in[12];
  const float* ln1g = (const float*)d_in[13];
  const float* ln1b = (const float*)d_in[14];
  const float* W1   = (const float*)d_in[15];
  const float* b1   = (const float*)d_in[16];
  const float* W2   = (const float*)d_in[17];
  const float* b2   = (const float*)d_in[18];
  const float* ln2g = (const float*)d_in[19];
  const float* ln2b = (const float*)d_in[20];
  const float* Wdn  = (const float*)d_in[21];
  const float* bdn  = (const float*)d_in[22];
  const float* Wdc  = (const float*)d_in[23];
  const float* bdc  = (const float*)d_in[24];
  const int* x_cat    = (const int*)d_in[25];
  const int* mask_num = (const int*)d_in[26];
  const int* mask_cat = (const int*)d_in[27];
  const int* pin      = (const int*)d_in[28];
  const int* pic      = (const int*)d_in[29];
  const int* cards    = (const int*)d_in[30];
  float* out = (float*)d_out;

  unsigned short* Wqkv_t = (unsigned short*)d_ws;           // 4*384*128
  unsigned short* Wo_t   = Wqkv_t + (size_t)4 * 384 * 128;  // 4*128*128
  unsigned short* W1_t   = Wo_t + (size_t)4 * 128 * 128;    // 4*512*128
  unsigned short* W2_t   = W1_t + (size_t)4 * 512 * 128;    // 4*128*512
  float* pe = (float*)(W2_t + (size_t)4 * 128 * 512);       // 16384 f32
  unsigned short* Xact = (unsigned short*)(pe + 16384);     // TOK*128
  unsigned short* Oact = Xact + (size_t)TOK * 128;          // TOK*128

  setup_kernel<<<3136, 256, 0, stream>>>(Wq, Wk, Wv, Wo, W1, W2,
      Wqkv_t, Wo_t, W1_t, W2_t, pe);

  embed_kernel<<<TOK / 2, 256, 0, stream>>>(x_num, W_numtok, b_numtok, E_cat,
      b_cattok, mask_tok, random_prob, rand_num, rand_cat, x_cat, mask_num,
      mask_cat, pe, Xact);

  for (int d = 0; d < cD; ++d) {
    qkv_attn_kernel<<<cB * 4, 512, 0, stream>>>(
        Xact, Wqkv_t + (size_t)d * 384 * 128, Oact);
    ffn_kernel<<<TOK / 128, 512, 0, stream>>>(
        Oact, Xact, Wo_t + (size_t)d * 128 * 128,
        W1_t + (size_t)d * 512 * 128, W2_t + (size_t)d * 128 * 512,
        ln1g + d * cE, ln1b + d * cE, ln2g + d * cE, ln2b + d * cE,
        b1 + d * cFF, b2 + d * cE);
  }

  decode_kernel<<<cB, 64, 0, stream>>>(Xact, Wdn, bdn, Wdc, bdc, pin, pic, cards, out);
}